// Round 18
// baseline (506.217 us; speedup 1.0000x reference)
//
#include <hip/hip_runtime.h>

// ---------- types ----------
typedef __attribute__((ext_vector_type(8))) short  s8v;    // 8 bf16 (as shorts) = 4 VGPR
typedef __attribute__((ext_vector_type(8))) unsigned short us8;
typedef __attribute__((ext_vector_type(4))) unsigned short us4;
typedef __attribute__((ext_vector_type(4))) float  f4v;    // MFMA accumulator

// float -> bf16 round-to-nearest-even (inputs are finite)
__device__ __forceinline__ unsigned short f2bf(float f) {
  unsigned int u = __builtin_bit_cast(unsigned int, f);
  u += 0x7fffu + ((u >> 16) & 1u);
  return (unsigned short)(u >> 16);
}

// async global->LDS, 16B per lane; offset arg must stay 0 (only verified mode).
__device__ __forceinline__ void gll16(const void* g, void* l) {
  __builtin_amdgcn_global_load_lds(
      (const __attribute__((address_space(1))) unsigned int*)g,
      (__attribute__((address_space(3))) unsigned int*)l, 16, 0, 0);
}

// ---------- kernel 1: x fp32 -> bf16 ----------
__global__ __launch_bounds__(256) void cast_bf16(const float* __restrict__ in,
                                                 unsigned short* __restrict__ out) {
  const size_t i = (size_t)blockIdx.x * 256 + threadIdx.x;
  const f4v* p = (const f4v*)in;
  f4v a = p[2 * i];
  f4v b = p[2 * i + 1];
  us8 r;
  r[0] = f2bf(a[0]); r[1] = f2bf(a[1]); r[2] = f2bf(a[2]); r[3] = f2bf(a[3]);
  r[4] = f2bf(b[0]); r[5] = f2bf(b[1]); r[6] = f2bf(b[2]); r[7] = f2bf(b[3]);
  *(us8*)&out[i * 8] = r;
}

// ---------- kernel 2: T[(o1i1)*256+(o2i2)][r2] = sum_r1 c0*c1, bf16 out ----------
__global__ __launch_bounds__(256) void contract1b(const float* __restrict__ c0,
                                                  const float* __restrict__ c1,
                                                  unsigned short* __restrict__ T) {
  const int idx = blockIdx.x * 256 + threadIdx.x;   // 1,048,576
  const int r2q = idx & 15;
  const int oi2 = (idx >> 4) & 255;
  const int oi1 = idx >> 12;
  const float* c0p = c0 + oi1 * 64;
  const float* c1p = c1 + oi2 * 64 + r2q * 4;
  f4v s = (f4v)0.f;
#pragma unroll 8
  for (int r1 = 0; r1 < 64; ++r1) {
    const float t = c0p[r1];
    const f4v v = *(const f4v*)(c1p + r1 * 16384);
    s[0] = fmaf(t, v[0], s[0]); s[1] = fmaf(t, v[1], s[1]);
    s[2] = fmaf(t, v[2], s[2]); s[3] = fmaf(t, v[3], s[3]);
  }
  us4 o;
  o[0] = f2bf(s[0]); o[1] = f2bf(s[1]); o[2] = f2bf(s[2]); o[3] = f2bf(s[3]);
  *(us4*)&T[(size_t)idx * 4] = o;
}

// ---------- kernel 2b: c2t[n=o3*16+i3][k=r2] bf16 = c2[r2][n] ----------
__global__ __launch_bounds__(256) void transc2(const float* __restrict__ c2,
                                               unsigned short* __restrict__ c2t) {
  const int n = blockIdx.x * 16 + (threadIdx.x >> 4);
  const int j = threadIdx.x & 15;
  us4 o;
#pragma unroll
  for (int q = 0; q < 4; ++q) o[q] = f2bf(c2[(j * 4 + q) * 256 + n]);
  *(us4*)&c2t[(size_t)n * 64 + j * 4] = o;
}

// ---------- kernel 3: buildW3 — 256x256x64 MFMA mini-GEMM per (o1,o2) ----------
__global__ __launch_bounds__(256) void buildW3(const unsigned short* __restrict__ T,
                                               const unsigned short* __restrict__ c2t,
                                               unsigned short* __restrict__ W) {
  __shared__ unsigned short sT[16384];  // 32 KB [m 256][k 64] swizzled
  __shared__ unsigned short sC[16384];  // 32 KB [n 256][k 64] swizzled

  const int tid = threadIdx.x;
  const int o1 = blockIdx.x >> 4, o2 = blockIdx.x & 15;

#pragma unroll
  for (int j = 0; j < 8; ++j) {
    const int c = j * 256 + tid;
    const int m = c >> 3, sl = c & 7;
    const int dst = m * 64 + ((sl ^ (m & 7)) << 3);
    *(us8*)&sT[dst] = *(const us8*)(T + (size_t)(o1 * 16 + (m >> 4)) * 16384 +
                                    (o2 * 16 + (m & 15)) * 64 + sl * 8);
    *(us8*)&sC[dst] = *(const us8*)(c2t + (size_t)m * 64 + sl * 8);
  }
  __syncthreads();

  const int lane = tid & 63, wid = tid >> 6;
  const int fr = lane & 15, ks = lane >> 4;
  const int f7 = fr & 7;
  const int sx0 = ((ks ^ f7) << 3);
  const int sx1 = (((4 + ks) ^ f7) << 3);

  s8v a[4][2];
#pragma unroll
  for (int mi = 0; mi < 4; ++mi) {
    const unsigned short* p = &sT[(wid * 64 + mi * 16 + fr) * 64];
    a[mi][0] = *(const s8v*)(p + sx0);
    a[mi][1] = *(const s8v*)(p + sx1);
  }
#pragma unroll
  for (int nt = 0; nt < 16; ++nt) {
    const unsigned short* p = &sC[(nt * 16 + fr) * 64];
    const s8v b0 = *(const s8v*)(p + sx0);
    const s8v b1 = *(const s8v*)(p + sx1);
#pragma unroll
    for (int mi = 0; mi < 4; ++mi) {
      f4v acc = (f4v)0.f;
      acc = __builtin_amdgcn_mfma_f32_16x16x32_bf16(a[mi][0], b0, acc, 0, 0, 0);
      acc = __builtin_amdgcn_mfma_f32_16x16x32_bf16(a[mi][1], b1, acc, 0, 0, 0);
      unsigned short* wp = W + (size_t)(o1 * 256 + o2 * 16 + nt) * 4096 +
                           (wid * 4 + mi) * 256 + fr;
#pragma unroll
      for (int r = 0; r < 4; ++r) wp[(ks * 4 + r) * 16] = f2bf(acc[r]);
    }
  }
}

// ---------- kernel 4: 256x256-tile GEMM, every-read-covered 8-window pipeline ----------
// A[M][K], B[N][K] bf16, C[M][N] fp32. M=8192, N=4096, K=4096.
// buf0=even K-tiles @0, buf1=odd @32768. Per buf: Alo@0,Ahi@8192,Blo@16384,Bhi@24576.
// Swizzle slot^row&7 both sides (0 conflicts, proven).
// RULE (the m201 overlap mechanism): every ds_read is issued >=1 full MFMA
// cluster (~310cy/wave) + 1 barrier before its consuming MFMA -> all compiler
// lgkm waits are counted (4/8/12), never full drains. Per tile c (4 windows):
//  W1: rd a1(c);                MM Q00(a0,b0);            SBAR
//  W2: STG Alo,Blo(c+2);        MM Q01(a0,b1);  VMW(4);   SBAR   <- publishes c+1
//  W3: rd a0(c+1); MM Q10(a1,b0); rd b0(c+1); STG Bhi(c+2); SBAR
//  W4: MM Q11(a1,b1); rd b1(c+1); STG Ahi(c+2);           SBAR
// (b0/b1 refills sit AFTER the mmq that last reads the old bank: reg-WAR safe.)
// Region WAR: each STG target's last consumer lgkm-proves completion >=1 barrier
// before the STG. VMW(4) invariant: queue=12 {c+1's 8 (issued W2-W4 of c-1) +
// just-issued Alo,Blo(c+2) 4}; drains exactly c+1, leaves 4. Stages for tile X
// all happen in tile X-2's windows -> flight 4-6 windows >> 900cy HBM.

#define SBAR() do { asm volatile("" ::: "memory"); __builtin_amdgcn_s_barrier(); asm volatile("" ::: "memory"); } while (0)
#define VMW(N) asm volatile("s_waitcnt vmcnt(" #N ")" ::: "memory")

template<int MQ, int NQ>
__device__ __forceinline__ void mmq(f4v (&acc)[8][4], const s8v (&a)[4][2], const s8v (&b)[2][2]) {
  __builtin_amdgcn_s_setprio(1);
#pragma unroll
  for (int mi = 0; mi < 4; ++mi)
#pragma unroll
    for (int ni = 0; ni < 2; ++ni)
#pragma unroll
      for (int q = 0; q < 2; ++q)
        acc[MQ * 4 + mi][NQ * 2 + ni] = __builtin_amdgcn_mfma_f32_16x16x32_bf16(
            a[mi][q], b[ni][q], acc[MQ * 4 + mi][NQ * 2 + ni], 0, 0, 0);
  __builtin_amdgcn_s_setprio(0);
}

__global__ __launch_bounds__(512, 2) void gemm8(const unsigned short* __restrict__ A,
                                                const unsigned short* __restrict__ B,
                                                float* __restrict__ C) {
  constexpr int N = 4096, K = 4096;
  constexpr int NT = K / 64;
  constexpr int NITER = NT / 2;     // 32 iters, 2 K-tiles each
  constexpr int NXT = N / 256;

  __shared__ unsigned short lds[65536];   // 128 KiB

  const int tid  = threadIdx.x;
  const int lane = tid & 63;
  const int wid  = tid >> 6;
  const int wm   = wid >> 2;
  const int wn   = wid & 3;

  const int cpx = (int)gridDim.x >> 3;
  const int wg  = ((int)blockIdx.x & 7) * cpx + ((int)blockIdx.x >> 3);
  const long bm = (long)(wg / NXT) * 256;
  const long bn = (long)(wg % NXT) * 256;

  const int srow = tid >> 3;
  const int scol = ((tid & 7) ^ (srow & 7)) * 8;
  const unsigned short* gA = A + (bm + srow) * (size_t)K + scol;
  const unsigned short* gB = B + (bn + srow) * (size_t)K + scol;
  const size_t half64 = 64 * (size_t)K;
  const size_t k128   = 128 * (size_t)K;

#define STG(gp, koff, ldsU) do {                                  \
    const unsigned short* g_ = (gp) + (koff);                     \
    gll16(g_,          &lds[(ldsU) + tid * 8]);                   \
    gll16(g_ + half64, &lds[(ldsU) + 4096 + tid * 8]);            \
  } while (0)

  const int fr = lane & 15;
  const int ks = lane >> 4;
  const int f7 = fr & 7;
  const int sx0 = (ks ^ f7) * 8;
  const int sx1 = ((ks | 4) ^ f7) * 8;
  const int arow = (wm * 64 + fr) * 64;
  const int brow = (wn * 32 + fr) * 64;

#define RDA(dst, MQ, bufU) do {                                              \
    const unsigned short* p_ = &lds[(bufU) + (MQ) * 8192 + arow];            \
    dst[0][0] = *(const s8v*)(p_ + sx0);        dst[0][1] = *(const s8v*)(p_ + sx1); \
    dst[1][0] = *(const s8v*)(p_ + 1024 + sx0); dst[1][1] = *(const s8v*)(p_ + 1024 + sx1); \
    dst[2][0] = *(const s8v*)(p_ + 2048 + sx0); dst[2][1] = *(const s8v*)(p_ + 2048 + sx1); \
    dst[3][0] = *(const s8v*)(p_ + 3072 + sx0); dst[3][1] = *(const s8v*)(p_ + 3072 + sx1); \
  } while (0)
#define RDB(dst, NQ, bufU) do {                                              \
    const unsigned short* p_ = &lds[(bufU) + 16384 + (NQ) * 8192 + brow];    \
    dst[0][0] = *(const s8v*)(p_ + sx0);        dst[0][1] = *(const s8v*)(p_ + sx1); \
    dst[1][0] = *(const s8v*)(p_ + 1024 + sx0); dst[1][1] = *(const s8v*)(p_ + 1024 + sx1); \
  } while (0)

  f4v acc[8][4];
#pragma unroll
  for (int m = 0; m < 8; ++m)
#pragma unroll
    for (int n = 0; n < 4; ++n) acc[m][n] = (f4v)0.0f;

  // prologue: c0 all 4 halves (buf0) + Alo,Blo(c1) (W2-role); VMW(4) drains c0,
  // leaves c1's 4; pub barrier; then W3/W4-role reads of c0 + Bhi,Ahi(c1) stages.
  STG(gA,        0, 0);
  STG(gA + k128, 0, 8192);
  STG(gB,        0, 16384);
  STG(gB + k128, 0, 24576);
  STG(gA,        64, 32768);          // Alo(c1)
  STG(gB,        64, 32768 + 16384);  // Blo(c1)
  VMW(4);
  SBAR();                             // publishes c0

  s8v a0[4][2], a1[4][2], b0[2][2], b1[2][2];
  RDA(a0, 0, 0);                      // a0(c0)
  RDB(b0, 0, 0);                      // b0(c0)
  STG(gB + k128, 64, 32768 + 24576);  // Bhi(c1)
  RDB(b1, 1, 0);                      // b1(c0)
  STG(gA + k128, 64, 32768 + 8192);   // Ahi(c1)
  SBAR();

  for (int i = 0; i < NITER; ++i) {
    const long w2 = (i == NITER - 1) ? -128L : 0L;   // wrap c0+2 dummy stages
    const long w3 = (i == NITER - 1) ? -192L : 0L;   // wrap c1+2 dummy stages
    // ======== tile c0 (buf0), next = c1 (buf1), stages -> c0+2 (buf0) ========
    // W1
    RDA(a1, 1, 0);
    mmq<0, 0>(acc, a0, b0);
    SBAR();
    // W2
    STG(gA, 128 + w2, 0);
    STG(gB, 128 + w2, 16384);
    mmq<0, 1>(acc, a0, b1);
    VMW(4);
    SBAR();                            // publishes c1
    // W3
    RDA(a0, 0, 32768);
    mmq<1, 0>(acc, a1, b0);
    RDB(b0, 0, 32768);
    STG(gB + k128, 128 + w2, 24576);
    SBAR();
    // W4
    mmq<1, 1>(acc, a1, b1);
    RDB(b1, 1, 32768);
    STG(gA + k128, 128 + w2, 8192);
    SBAR();
    // ======== tile c1 (buf1), next = c0+2 (buf0), stages -> c1+2 (buf1) ========
    // W1
    RDA(a1, 1, 32768);
    mmq<0, 0>(acc, a0, b0);
    SBAR();
    // W2
    STG(gA, 192 + w3, 32768);
    STG(gB, 192 + w3, 32768 + 16384);
    mmq<0, 1>(acc, a0, b1);
    VMW(4);
    SBAR();                            // publishes c0+2
    // W3
    RDA(a0, 0, 0);
    mmq<1, 0>(acc, a1, b0);
    RDB(b0, 0, 0);
    STG(gB + k128, 192 + w3, 32768 + 24576);
    SBAR();
    // W4
    mmq<1, 1>(acc, a1, b1);
    RDB(b1, 1, 0);
    STG(gA + k128, 192 + w3, 32768 + 8192);
    SBAR();

    gA += 128; gB += 128;
  }
  VMW(0);          // drain remaining dummy prefetches

  // ---- epilogue: row = bm + mq*128 + wm*64 + mi*16 + ks*4 + r ; col = bn + nq*128 + wn*32 + ni*16 + fr
#pragma unroll
  for (int mq = 0; mq < 2; ++mq)
#pragma unroll
    for (int mi = 0; mi < 4; ++mi)
#pragma unroll
      for (int nq = 0; nq < 2; ++nq)
#pragma unroll
        for (int ni = 0; ni < 2; ++ni) {
          const size_t row0 = bm + mq * 128 + wm * 64 + mi * 16 + ks * 4;
          const size_t col  = bn + nq * 128 + wn * 32 + ni * 16 + fr;
          float* cp = C + row0 * (size_t)N + col;
          f4v v = acc[mq * 4 + mi][nq * 2 + ni];
          cp[0] = v[0]; cp[N] = v[1]; cp[2 * (size_t)N] = v[2]; cp[3 * (size_t)N] = v[3];
        }
#undef STG
#undef RDA
#undef RDB
}

// ---------- launch ----------
extern "C" void kernel_launch(void* const* d_in, const int* in_sizes, int n_in,
                              void* d_out, int out_size, void* d_ws, size_t ws_size,
                              hipStream_t stream) {
  const float* x  = (const float*)d_in[0];   // [8192,4096]
  const float* c0 = (const float*)d_in[1];   // [1,16,16,64]
  const float* c1 = (const float*)d_in[2];   // [64,16,16,64]
  const float* c2 = (const float*)d_in[3];   // [64,16,16,1]
  float* out = (float*)d_out;                // [8192,4096] fp32

  char* ws = (char*)d_ws;
  unsigned short* T   = (unsigned short*)ws;                      // 8 MB  bf16
  unsigned short* c2t = (unsigned short*)(ws + (8u << 20));       // 32 KB bf16
  unsigned short* Wb  = (unsigned short*)(ws + (16u << 20));      // 32 MB bf16
  unsigned short* xb  = (unsigned short*)(ws + (48u << 20));      // 64 MB bf16

  hipLaunchKernelGGL(cast_bf16,  dim3(16384), dim3(256), 0, stream, x, xb);
  hipLaunchKernelGGL(contract1b, dim3(4096),  dim3(256), 0, stream, c0, c1, T);
  hipLaunchKernelGGL(transc2,    dim3(16),    dim3(256), 0, stream, c2, c2t);
  hipLaunchKernelGGL(buildW3,    dim3(256),   dim3(256), 0, stream, T, c2t, Wb);
  hipLaunchKernelGGL(gemm8,      dim3(512),   dim3(512), 0, stream, xb, Wb, out);
}

// Round 19
// 276.201 us; speedup vs baseline: 1.8328x; 1.8328x over previous
//
#include <hip/hip_runtime.h>

// ---------- types ----------
typedef __attribute__((ext_vector_type(8))) short  s8v;    // 8 bf16 (as shorts) = 4 VGPR
typedef __attribute__((ext_vector_type(8))) unsigned short us8;
typedef __attribute__((ext_vector_type(4))) unsigned short us4;
typedef __attribute__((ext_vector_type(4))) float  f4v;    // MFMA accumulator

// float -> bf16 round-to-nearest-even (inputs are finite)
__device__ __forceinline__ unsigned short f2bf(float f) {
  unsigned int u = __builtin_bit_cast(unsigned int, f);
  u += 0x7fffu + ((u >> 16) & 1u);
  return (unsigned short)(u >> 16);
}

// async global->LDS, 16B per lane; offset arg must stay 0 (only verified mode).
__device__ __forceinline__ void gll16(const void* g, void* l) {
  __builtin_amdgcn_global_load_lds(
      (const __attribute__((address_space(1))) unsigned int*)g,
      (__attribute__((address_space(3))) unsigned int*)l, 16, 0, 0);
}

// ---------- kernel 1: x fp32 -> bf16 (33.5M elems) ----------
__global__ __launch_bounds__(256) void cast_bf16(const float* __restrict__ in,
                                                 unsigned short* __restrict__ out) {
  const size_t i = (size_t)blockIdx.x * 256 + threadIdx.x;
  const f4v* p = (const f4v*)in;
  f4v a = p[2 * i];
  f4v b = p[2 * i + 1];
  us8 r;
  r[0] = f2bf(a[0]); r[1] = f2bf(a[1]); r[2] = f2bf(a[2]); r[3] = f2bf(a[3]);
  r[4] = f2bf(b[0]); r[5] = f2bf(b[1]); r[6] = f2bf(b[2]); r[7] = f2bf(b[3]);
  *(us8*)&out[i * 8] = r;
}

// ---------- kernel 1b: c0 fp32 -> bf16 (16384 elems; grid 8 x 256) ----------
__global__ __launch_bounds__(256) void cast_c0(const float* __restrict__ in,
                                               unsigned short* __restrict__ out) {
  const size_t i = (size_t)blockIdx.x * 256 + threadIdx.x;
  const f4v* p = (const f4v*)in;
  f4v a = p[2 * i];
  f4v b = p[2 * i + 1];
  us8 r;
  r[0] = f2bf(a[0]); r[1] = f2bf(a[1]); r[2] = f2bf(a[2]); r[3] = f2bf(a[3]);
  r[4] = f2bf(b[0]); r[5] = f2bf(b[1]); r[6] = f2bf(b[2]); r[7] = f2bf(b[3]);
  *(us8*)&out[i * 8] = r;
}

// ---------- kernel 2a: tc1 — transpose-cast c1[k=64][n=16384] fp32 -> c1t[n][k] bf16 ----------
// Block nb handles n in [nb*256, nb*256+256). LDS tile [64 k][256 n] fp32 (64 KB).
// Stage coalesced f4v; write phase: lane nn reads Tl[k][nn] (bank = nn%32, 2 lanes/bank
// = free) and writes us4 (4 k) to c1t[n][k] rows.
__global__ __launch_bounds__(256) void tc1(const float* __restrict__ c1,
                                           unsigned short* __restrict__ c1t) {
  __shared__ float Tl[16384];   // [k=64][n=256]
  const int tid = threadIdx.x;
  const int nb  = blockIdx.x;
#pragma unroll
  for (int j = 0; j < 16; ++j) {
    const int c = j * 256 + tid;           // 0..4095 f4v chunks
    const int k = c >> 6, nq = c & 63;
    *(f4v*)&Tl[k * 256 + nq * 4] =
        *(const f4v*)(c1 + (size_t)k * 16384 + nb * 256 + nq * 4);
  }
  __syncthreads();
  const int nn = tid;                      // 0..255
  unsigned short* dst = c1t + (size_t)(nb * 256 + nn) * 64;
#pragma unroll
  for (int kq = 0; kq < 16; ++kq) {
    us4 o;
#pragma unroll
    for (int r = 0; r < 4; ++r) o[r] = f2bf(Tl[(kq * 4 + r) * 256 + nn]);
    *(us4*)&dst[kq * 4] = o;
  }
}

// ---------- kernel 2b: tgemm — T[m=256][n=16384] = c0bf[m][k=64] * c1t[n][k]^T ----------
// 128x256 tile, single K=64 shot. Staging swizzle (slot^row&7), fragment reads
// (sx0/sx1), and D-layout write copied from the verified main GEMM.
// Grid (64 nb, 2 mb), 512 threads (8 waves: wm=wid>>2 M-64-half, wn=wid&3 N-64-quarter).
__global__ __launch_bounds__(512) void tgemm(const unsigned short* __restrict__ c0bf,
                                             const unsigned short* __restrict__ c1t,
                                             unsigned short* __restrict__ T) {
  __shared__ unsigned short sA[8192];    // [128 m][64 k] swizzled
  __shared__ unsigned short sB[16384];   // [256 n][64 k] swizzled

  const int tid = threadIdx.x;
  const int nb = blockIdx.x, mb = blockIdx.y;

#pragma unroll
  for (int j = 0; j < 2; ++j) {
    const int c = j * 512 + tid;           // 0..1023
    const int row = c >> 3, sl = c & 7;
    *(us8*)&sA[row * 64 + ((sl ^ (row & 7)) << 3)] =
        *(const us8*)(c0bf + (size_t)(mb * 128 + row) * 64 + sl * 8);
  }
#pragma unroll
  for (int j = 0; j < 4; ++j) {
    const int c = j * 512 + tid;           // 0..2047
    const int row = c >> 3, sl = c & 7;
    *(us8*)&sB[row * 64 + ((sl ^ (row & 7)) << 3)] =
        *(const us8*)(c1t + (size_t)(nb * 256 + row) * 64 + sl * 8);
  }
  __syncthreads();

  const int lane = tid & 63, wid = tid >> 6;
  const int wm = wid >> 2, wn = wid & 3;
  const int fr = lane & 15, ks = lane >> 4;
  const int f7 = fr & 7;
  const int sx0 = (ks ^ f7) * 8;
  const int sx1 = ((ks | 4) ^ f7) * 8;

  s8v a[4][2], b[4][2];
#pragma unroll
  for (int mi = 0; mi < 4; ++mi) {
    const unsigned short* p = &sA[(wm * 64 + mi * 16 + fr) * 64];
    a[mi][0] = *(const s8v*)(p + sx0);
    a[mi][1] = *(const s8v*)(p + sx1);
  }
#pragma unroll
  for (int ni = 0; ni < 4; ++ni) {
    const unsigned short* p = &sB[(wn * 64 + ni * 16 + fr) * 64];
    b[ni][0] = *(const s8v*)(p + sx0);
    b[ni][1] = *(const s8v*)(p + sx1);
  }

  f4v acc[4][4];
#pragma unroll
  for (int mi = 0; mi < 4; ++mi)
#pragma unroll
    for (int ni = 0; ni < 4; ++ni) {
      acc[mi][ni] = (f4v)0.f;
      acc[mi][ni] = __builtin_amdgcn_mfma_f32_16x16x32_bf16(a[mi][0], b[ni][0], acc[mi][ni], 0, 0, 0);
      acc[mi][ni] = __builtin_amdgcn_mfma_f32_16x16x32_bf16(a[mi][1], b[ni][1], acc[mi][ni], 0, 0, 0);
    }

  // D: col = lane&15 (B-side), row = ks*4 + r (A-side)
#pragma unroll
  for (int mi = 0; mi < 4; ++mi)
#pragma unroll
    for (int ni = 0; ni < 4; ++ni) {
      const int row0 = mb * 128 + wm * 64 + mi * 16 + ks * 4;
      const size_t col = (size_t)nb * 256 + wn * 64 + ni * 16 + fr;
#pragma unroll
      for (int r = 0; r < 4; ++r)
        T[(size_t)(row0 + r) * 16384 + col] = f2bf(acc[mi][ni][r]);
    }
}

// ---------- kernel 2c: c2t[n=o3*16+i3][k=r2] bf16 = c2[r2][n] ----------
__global__ __launch_bounds__(256) void transc2(const float* __restrict__ c2,
                                               unsigned short* __restrict__ c2t) {
  const int n = blockIdx.x * 16 + (threadIdx.x >> 4);
  const int j = threadIdx.x & 15;
  us4 o;
#pragma unroll
  for (int q = 0; q < 4; ++q) o[q] = f2bf(c2[(j * 4 + q) * 256 + n]);
  *(us4*)&c2t[(size_t)n * 64 + j * 4] = o;
}

// ---------- kernel 3: buildW3 — 256x256x64 MFMA mini-GEMM per (o1,o2) ----------
__global__ __launch_bounds__(256) void buildW3(const unsigned short* __restrict__ T,
                                               const unsigned short* __restrict__ c2t,
                                               unsigned short* __restrict__ W) {
  __shared__ unsigned short sT[16384];  // 32 KB [m 256][k 64] swizzled
  __shared__ unsigned short sC[16384];  // 32 KB [n 256][k 64] swizzled

  const int tid = threadIdx.x;
  const int o1 = blockIdx.x >> 4, o2 = blockIdx.x & 15;

#pragma unroll
  for (int j = 0; j < 8; ++j) {
    const int c = j * 256 + tid;
    const int m = c >> 3, sl = c & 7;
    const int dst = m * 64 + ((sl ^ (m & 7)) << 3);
    *(us8*)&sT[dst] = *(const us8*)(T + (size_t)(o1 * 16 + (m >> 4)) * 16384 +
                                    (o2 * 16 + (m & 15)) * 64 + sl * 8);
    *(us8*)&sC[dst] = *(const us8*)(c2t + (size_t)m * 64 + sl * 8);
  }
  __syncthreads();

  const int lane = tid & 63, wid = tid >> 6;
  const int fr = lane & 15, ks = lane >> 4;
  const int f7 = fr & 7;
  const int sx0 = ((ks ^ f7) << 3);
  const int sx1 = (((4 + ks) ^ f7) << 3);

  s8v a[4][2];
#pragma unroll
  for (int mi = 0; mi < 4; ++mi) {
    const unsigned short* p = &sT[(wid * 64 + mi * 16 + fr) * 64];
    a[mi][0] = *(const s8v*)(p + sx0);
    a[mi][1] = *(const s8v*)(p + sx1);
  }
#pragma unroll
  for (int nt = 0; nt < 16; ++nt) {
    const unsigned short* p = &sC[(nt * 16 + fr) * 64];
    const s8v b0 = *(const s8v*)(p + sx0);
    const s8v b1 = *(const s8v*)(p + sx1);
#pragma unroll
    for (int mi = 0; mi < 4; ++mi) {
      f4v acc = (f4v)0.f;
      acc = __builtin_amdgcn_mfma_f32_16x16x32_bf16(a[mi][0], b0, acc, 0, 0, 0);
      acc = __builtin_amdgcn_mfma_f32_16x16x32_bf16(a[mi][1], b1, acc, 0, 0, 0);
      unsigned short* wp = W + (size_t)(o1 * 256 + o2 * 16 + nt) * 4096 +
                           (wid * 4 + mi) * 256 + fr;
#pragma unroll
      for (int r = 0; r < 4; ++r) wp[(ks * 4 + r) * 16] = f2bf(acc[r]);
    }
  }
}

// ---------- kernel 4: 256x256-tile GEMM (exact R13 best: 238us, MfmaUtil 53) ----------
#define SBAR() do { asm volatile("" ::: "memory"); __builtin_amdgcn_s_barrier(); asm volatile("" ::: "memory"); } while (0)
#define VMW(N) asm volatile("s_waitcnt vmcnt(" #N ")" ::: "memory")

template<int MQ, int NQ>
__device__ __forceinline__ void mmq(f4v (&acc)[8][4], const s8v (&a)[4][2], const s8v (&b)[2][2]) {
  __builtin_amdgcn_s_setprio(1);
#pragma unroll
  for (int mi = 0; mi < 4; ++mi)
#pragma unroll
    for (int ni = 0; ni < 2; ++ni)
#pragma unroll
      for (int q = 0; q < 2; ++q)
        acc[MQ * 4 + mi][NQ * 2 + ni] = __builtin_amdgcn_mfma_f32_16x16x32_bf16(
            a[mi][q], b[ni][q], acc[MQ * 4 + mi][NQ * 2 + ni], 0, 0, 0);
  __builtin_amdgcn_s_setprio(0);
}

__global__ __launch_bounds__(512, 2) void gemm8(const unsigned short* __restrict__ A,
                                                const unsigned short* __restrict__ B,
                                                float* __restrict__ C) {
  constexpr int N = 4096, K = 4096;
  constexpr int NT = K / 64;
  constexpr int NITER = NT / 2;     // 32 iters, 2 K-tiles each
  constexpr int NXT = N / 256;

  __shared__ unsigned short lds[65536];   // 128 KiB

  const int tid  = threadIdx.x;
  const int lane = tid & 63;
  const int wid  = tid >> 6;
  const int wm   = wid >> 2;
  const int wn   = wid & 3;

  const int cpx = (int)gridDim.x >> 3;
  const int wg  = ((int)blockIdx.x & 7) * cpx + ((int)blockIdx.x >> 3);
  const long bm = (long)(wg / NXT) * 256;
  const long bn = (long)(wg % NXT) * 256;

  const int srow = tid >> 3;
  const int scol = ((tid & 7) ^ (srow & 7)) * 8;
  const unsigned short* gA = A + (bm + srow) * (size_t)K + scol;
  const unsigned short* gB = B + (bn + srow) * (size_t)K + scol;
  const size_t half64 = 64 * (size_t)K;
  const size_t k128   = 128 * (size_t)K;

#define STG(gp, koff, ldsU) do {                                  \
    const unsigned short* g_ = (gp) + (koff);                     \
    gll16(g_,          &lds[(ldsU) + tid * 8]);                   \
    gll16(g_ + half64, &lds[(ldsU) + 4096 + tid * 8]);            \
  } while (0)

  const int fr = lane & 15;
  const int ks = lane >> 4;
  const int f7 = fr & 7;
  const int sx0 = (ks ^ f7) * 8;
  const int sx1 = ((ks | 4) ^ f7) * 8;
  const int arow = (wm * 64 + fr) * 64;
  const int brow = (wn * 32 + fr) * 64;

#define RDA(MQ, bufU) do {                                                   \
    const unsigned short* p_ = &lds[(bufU) + (MQ) * 8192 + arow];            \
    a[0][0] = *(const s8v*)(p_ + sx0);        a[0][1] = *(const s8v*)(p_ + sx1); \
    a[1][0] = *(const s8v*)(p_ + 1024 + sx0); a[1][1] = *(const s8v*)(p_ + 1024 + sx1); \
    a[2][0] = *(const s8v*)(p_ + 2048 + sx0); a[2][1] = *(const s8v*)(p_ + 2048 + sx1); \
    a[3][0] = *(const s8v*)(p_ + 3072 + sx0); a[3][1] = *(const s8v*)(p_ + 3072 + sx1); \
  } while (0)
#define RDB(dst, NQ, bufU) do {                                              \
    const unsigned short* p_ = &lds[(bufU) + 16384 + (NQ) * 8192 + brow];    \
    dst[0][0] = *(const s8v*)(p_ + sx0);        dst[0][1] = *(const s8v*)(p_ + sx1); \
    dst[1][0] = *(const s8v*)(p_ + 1024 + sx0); dst[1][1] = *(const s8v*)(p_ + 1024 + sx1); \
  } while (0)

  f4v acc[8][4];
#pragma unroll
  for (int m = 0; m < 8; ++m)
#pragma unroll
    for (int n = 0; n < 4; ++n) acc[m][n] = (f4v)0.0f;

  // prologue: tile0 all 4 halves -> buf0; Alo(t1) -> buf1
  STG(gA,        0, 0);
  STG(gA + k128, 0, 8192);
  STG(gB,        0, 16384);
  STG(gB + k128, 0, 24576);
  STG(gA,        64, 32768);
  VMW(2);          // tile0's 8 loads drained; Alo(t1) flies
  SBAR();

  s8v a[4][2], bL[2][2], bH[2][2];

  for (int i = 0; i < NITER; ++i) {
    const long w46 = (i == NITER - 1) ? -128L : 0L;
    const long w8  = (i == NITER - 1) ? -192L : 0L;
    // ---- P1: pre {aLo,bL,bH}(c0); STG Blo(c1); MM(0,0) ----
    RDA(0, 0); RDB(bL, 0, 0); RDB(bH, 1, 0);
    STG(gB, 64, 32768 + 16384);
    SBAR(); mmq<0, 0>(acc, a, bL);
    // ---- P2: STG Ahi(c1)+Bhi(c1); MM(0,1); post-read aHi(c0) ----
    STG(gA + k128, 64, 32768 + 8192);
    STG(gB + k128, 64, 32768 + 24576);
    SBAR(); mmq<0, 1>(acc, a, bH);
    RDA(1, 0);
    // ---- P3: MM(1,0) ----
    SBAR(); mmq<1, 0>(acc, a, bL);
    // ---- P4: STG Alo(c0+2); MM(1,1); VMW(2) lands ALL c1; pub ----
    STG(gA, 128 + w46, 0);
    SBAR(); mmq<1, 1>(acc, a, bH);
    VMW(2); SBAR();
    // ---- P5: pre {aLo,bL,bH}(c1); STG Blo(c0+2); MM(0,0) ----
    RDA(0, 32768); RDB(bL, 0, 32768); RDB(bH, 1, 32768);
    STG(gB, 128 + w46, 16384);
    SBAR(); mmq<0, 0>(acc, a, bL);
    // ---- P6: STG Ahi(c0+2)+Bhi(c0+2); MM(0,1); post-read aHi(c1) ----
    STG(gA + k128, 128 + w46, 8192);
    STG(gB + k128, 128 + w46, 24576);
    SBAR(); mmq<0, 1>(acc, a, bH);
    RDA(1, 32768);
    // ---- P7: MM(1,0) ----
    SBAR(); mmq<1, 0>(acc, a, bL);
    // ---- P8: STG Alo(c1+2); MM(1,1); VMW(2) lands ALL c0+2; pub ----
    STG(gA, 192 + w8, 32768);
    SBAR(); mmq<1, 1>(acc, a, bH);
    VMW(2); SBAR();

    gA += 128; gB += 128;
  }
  VMW(0);          // drain dummy prefetches

#pragma unroll
  for (int mq = 0; mq < 2; ++mq)
#pragma unroll
    for (int mi = 0; mi < 4; ++mi)
#pragma unroll
      for (int nq = 0; nq < 2; ++nq)
#pragma unroll
        for (int ni = 0; ni < 2; ++ni) {
          const size_t row0 = bm + mq * 128 + wm * 64 + mi * 16 + ks * 4;
          const size_t col  = bn + nq * 128 + wn * 32 + ni * 16 + fr;
          float* cp = C + row0 * (size_t)N + col;
          f4v v = acc[mq * 4 + mi][nq * 2 + ni];
          cp[0] = v[0]; cp[N] = v[1]; cp[2 * (size_t)N] = v[2]; cp[3 * (size_t)N] = v[3];
        }
#undef STG
#undef RDA
#undef RDB
}

// ---------- launch ----------
extern "C" void kernel_launch(void* const* d_in, const int* in_sizes, int n_in,
                              void* d_out, int out_size, void* d_ws, size_t ws_size,
                              hipStream_t stream) {
  const float* x  = (const float*)d_in[0];   // [8192,4096]
  const float* c0 = (const float*)d_in[1];   // [1,16,16,64]
  const float* c1 = (const float*)d_in[2];   // [64,16,16,64]
  const float* c2 = (const float*)d_in[3];   // [64,16,16,1]
  float* out = (float*)d_out;                // [8192,4096] fp32

  char* ws = (char*)d_ws;
  unsigned short* T    = (unsigned short*)ws;                       // 8 MB  bf16 [256][16384]
  unsigned short* c2t  = (unsigned short*)(ws + (8u << 20));        // 32 KB bf16 [256][64]
  unsigned short* c0bf = (unsigned short*)(ws + (8u << 20) + 65536);// 32 KB bf16 [256][64]
  unsigned short* c1t  = (unsigned short*)(ws + (9u << 20));        // 2 MB  bf16 [16384][64]
  unsigned short* Wb   = (unsigned short*)(ws + (16u << 20));       // 32 MB bf16 [4096][4096]
  unsigned short* xb   = (unsigned short*)(ws + (48u << 20));       // 64 MB bf16 [8192][4096]

  hipLaunchKernelGGL(cast_bf16, dim3(16384), dim3(256), 0, stream, x, xb);
  hipLaunchKernelGGL(cast_c0,   dim3(8),     dim3(256), 0, stream, c0, c0bf);
  hipLaunchKernelGGL(tc1,       dim3(64),    dim3(256), 0, stream, c1, c1t);
  hipLaunchKernelGGL(tgemm,     dim3(64, 2), dim3(512), 0, stream, c0bf, c1t, T);
  hipLaunchKernelGGL(transc2,   dim3(16),    dim3(256), 0, stream, c2, c2t);
  hipLaunchKernelGGL(buildW3,   dim3(256),   dim3(256), 0, stream, T, c2t, Wb);
  hipLaunchKernelGGL(gemm8,     dim3(512),   dim3(512), 0, stream, xb, Wb, out);
}

// Round 20
// 275.805 us; speedup vs baseline: 1.8354x; 1.0014x over previous
//
#include <hip/hip_runtime.h>

// ---------- types ----------
typedef __attribute__((ext_vector_type(8))) short  s8v;    // 8 bf16 (as shorts) = 4 VGPR
typedef __attribute__((ext_vector_type(8))) unsigned short us8;
typedef __attribute__((ext_vector_type(4))) unsigned short us4;
typedef __attribute__((ext_vector_type(4))) float  f4v;    // MFMA accumulator

// float -> bf16 round-to-nearest-even (inputs are finite)
__device__ __forceinline__ unsigned short f2bf(float f) {
  unsigned int u = __builtin_bit_cast(unsigned int, f);
  u += 0x7fffu + ((u >> 16) & 1u);
  return (unsigned short)(u >> 16);
}

// async global->LDS, 16B per lane; offset arg must stay 0 (only verified mode).
__device__ __forceinline__ void gll16(const void* g, void* l) {
  __builtin_amdgcn_global_load_lds(
      (const __attribute__((address_space(1))) unsigned int*)g,
      (__attribute__((address_space(3))) unsigned int*)l, 16, 0, 0);
}

// ---------- kernel 1: x fp32 -> bf16 (33.5M elems) ----------
__global__ __launch_bounds__(256) void cast_bf16(const float* __restrict__ in,
                                                 unsigned short* __restrict__ out) {
  const size_t i = (size_t)blockIdx.x * 256 + threadIdx.x;
  const f4v* p = (const f4v*)in;
  f4v a = p[2 * i];
  f4v b = p[2 * i + 1];
  us8 r;
  r[0] = f2bf(a[0]); r[1] = f2bf(a[1]); r[2] = f2bf(a[2]); r[3] = f2bf(a[3]);
  r[4] = f2bf(b[0]); r[5] = f2bf(b[1]); r[6] = f2bf(b[2]); r[7] = f2bf(b[3]);
  *(us8*)&out[i * 8] = r;
}

// ---------- kernel 1b: c0 fp32 -> bf16 (16384 elems) ----------
__global__ __launch_bounds__(256) void cast_c0(const float* __restrict__ in,
                                               unsigned short* __restrict__ out) {
  const size_t i = (size_t)blockIdx.x * 256 + threadIdx.x;
  const f4v* p = (const f4v*)in;
  f4v a = p[2 * i];
  f4v b = p[2 * i + 1];
  us8 r;
  r[0] = f2bf(a[0]); r[1] = f2bf(a[1]); r[2] = f2bf(a[2]); r[3] = f2bf(a[3]);
  r[4] = f2bf(b[0]); r[5] = f2bf(b[1]); r[6] = f2bf(b[2]); r[7] = f2bf(b[3]);
  *(us8*)&out[i * 8] = r;
}

// ---------- kernel 2a: tc1 — transpose-cast c1[k=64][n=16384] fp32 -> c1t[n][k] bf16 ----------
__global__ __launch_bounds__(256) void tc1(const float* __restrict__ c1,
                                           unsigned short* __restrict__ c1t) {
  __shared__ float Tl[16384];   // [k=64][n=256]
  const int tid = threadIdx.x;
  const int nb  = blockIdx.x;
#pragma unroll
  for (int j = 0; j < 16; ++j) {
    const int c = j * 256 + tid;
    const int k = c >> 6, nq = c & 63;
    *(f4v*)&Tl[k * 256 + nq * 4] =
        *(const f4v*)(c1 + (size_t)k * 16384 + nb * 256 + nq * 4);
  }
  __syncthreads();
  const int nn = tid;
  unsigned short* dst = c1t + (size_t)(nb * 256 + nn) * 64;
#pragma unroll
  for (int kq = 0; kq < 16; ++kq) {
    us4 o;
#pragma unroll
    for (int r = 0; r < 4; ++r) o[r] = f2bf(Tl[(kq * 4 + r) * 256 + nn]);
    *(us4*)&dst[kq * 4] = o;
  }
}

// ---------- kernel 2b: tgemm — T[m=256][n=16384] = c0bf[m][k=64] * c1t[n][k]^T ----------
__global__ __launch_bounds__(512) void tgemm(const unsigned short* __restrict__ c0bf,
                                             const unsigned short* __restrict__ c1t,
                                             unsigned short* __restrict__ T) {
  __shared__ unsigned short sA[8192];    // [128 m][64 k] swizzled
  __shared__ unsigned short sB[16384];   // [256 n][64 k] swizzled

  const int tid = threadIdx.x;
  const int nb = blockIdx.x, mb = blockIdx.y;

#pragma unroll
  for (int j = 0; j < 2; ++j) {
    const int c = j * 512 + tid;
    const int row = c >> 3, sl = c & 7;
    *(us8*)&sA[row * 64 + ((sl ^ (row & 7)) << 3)] =
        *(const us8*)(c0bf + (size_t)(mb * 128 + row) * 64 + sl * 8);
  }
#pragma unroll
  for (int j = 0; j < 4; ++j) {
    const int c = j * 512 + tid;
    const int row = c >> 3, sl = c & 7;
    *(us8*)&sB[row * 64 + ((sl ^ (row & 7)) << 3)] =
        *(const us8*)(c1t + (size_t)(nb * 256 + row) * 64 + sl * 8);
  }
  __syncthreads();

  const int lane = tid & 63, wid = tid >> 6;
  const int wm = wid >> 2, wn = wid & 3;
  const int fr = lane & 15, ks = lane >> 4;
  const int f7 = fr & 7;
  const int sx0 = (ks ^ f7) * 8;
  const int sx1 = ((ks | 4) ^ f7) * 8;

  s8v a[4][2], b[4][2];
#pragma unroll
  for (int mi = 0; mi < 4; ++mi) {
    const unsigned short* p = &sA[(wm * 64 + mi * 16 + fr) * 64];
    a[mi][0] = *(const s8v*)(p + sx0);
    a[mi][1] = *(const s8v*)(p + sx1);
  }
#pragma unroll
  for (int ni = 0; ni < 4; ++ni) {
    const unsigned short* p = &sB[(wn * 64 + ni * 16 + fr) * 64];
    b[ni][0] = *(const s8v*)(p + sx0);
    b[ni][1] = *(const s8v*)(p + sx1);
  }

  f4v acc[4][4];
#pragma unroll
  for (int mi = 0; mi < 4; ++mi)
#pragma unroll
    for (int ni = 0; ni < 4; ++ni) {
      acc[mi][ni] = (f4v)0.f;
      acc[mi][ni] = __builtin_amdgcn_mfma_f32_16x16x32_bf16(a[mi][0], b[ni][0], acc[mi][ni], 0, 0, 0);
      acc[mi][ni] = __builtin_amdgcn_mfma_f32_16x16x32_bf16(a[mi][1], b[ni][1], acc[mi][ni], 0, 0, 0);
    }

#pragma unroll
  for (int mi = 0; mi < 4; ++mi)
#pragma unroll
    for (int ni = 0; ni < 4; ++ni) {
      const int row0 = mb * 128 + wm * 64 + mi * 16 + ks * 4;
      const size_t col = (size_t)nb * 256 + wn * 64 + ni * 16 + fr;
#pragma unroll
      for (int r = 0; r < 4; ++r)
        T[(size_t)(row0 + r) * 16384 + col] = f2bf(acc[mi][ni][r]);
    }
}

// ---------- kernel 2c: c2t[n=o3*16+i3][k=r2] bf16 = c2[r2][n] ----------
__global__ __launch_bounds__(256) void transc2(const float* __restrict__ c2,
                                               unsigned short* __restrict__ c2t) {
  const int n = blockIdx.x * 16 + (threadIdx.x >> 4);
  const int j = threadIdx.x & 15;
  us4 o;
#pragma unroll
  for (int q = 0; q < 4; ++q) o[q] = f2bf(c2[(j * 4 + q) * 256 + n]);
  *(us4*)&c2t[(size_t)n * 64 + j * 4] = o;
}

// ---------- kernel 3: buildW3 — 256x256x64 MFMA mini-GEMM per (o1,o2) ----------
__global__ __launch_bounds__(256) void buildW3(const unsigned short* __restrict__ T,
                                               const unsigned short* __restrict__ c2t,
                                               unsigned short* __restrict__ W) {
  __shared__ unsigned short sT[16384];
  __shared__ unsigned short sC[16384];

  const int tid = threadIdx.x;
  const int o1 = blockIdx.x >> 4, o2 = blockIdx.x & 15;

#pragma unroll
  for (int j = 0; j < 8; ++j) {
    const int c = j * 256 + tid;
    const int m = c >> 3, sl = c & 7;
    const int dst = m * 64 + ((sl ^ (m & 7)) << 3);
    *(us8*)&sT[dst] = *(const us8*)(T + (size_t)(o1 * 16 + (m >> 4)) * 16384 +
                                    (o2 * 16 + (m & 15)) * 64 + sl * 8);
    *(us8*)&sC[dst] = *(const us8*)(c2t + (size_t)m * 64 + sl * 8);
  }
  __syncthreads();

  const int lane = tid & 63, wid = tid >> 6;
  const int fr = lane & 15, ks = lane >> 4;
  const int f7 = fr & 7;
  const int sx0 = ((ks ^ f7) << 3);
  const int sx1 = (((4 + ks) ^ f7) << 3);

  s8v a[4][2];
#pragma unroll
  for (int mi = 0; mi < 4; ++mi) {
    const unsigned short* p = &sT[(wid * 64 + mi * 16 + fr) * 64];
    a[mi][0] = *(const s8v*)(p + sx0);
    a[mi][1] = *(const s8v*)(p + sx1);
  }
#pragma unroll
  for (int nt = 0; nt < 16; ++nt) {
    const unsigned short* p = &sC[(nt * 16 + fr) * 64];
    const s8v b0 = *(const s8v*)(p + sx0);
    const s8v b1 = *(const s8v*)(p + sx1);
#pragma unroll
    for (int mi = 0; mi < 4; ++mi) {
      f4v acc = (f4v)0.f;
      acc = __builtin_amdgcn_mfma_f32_16x16x32_bf16(a[mi][0], b0, acc, 0, 0, 0);
      acc = __builtin_amdgcn_mfma_f32_16x16x32_bf16(a[mi][1], b1, acc, 0, 0, 0);
      unsigned short* wp = W + (size_t)(o1 * 256 + o2 * 16 + nt) * 4096 +
                           (wid * 4 + mi) * 256 + fr;
#pragma unroll
      for (int r = 0; r < 4; ++r) wp[(ks * 4 + r) * 16] = f2bf(acc[r]);
    }
  }
}

// ---------- kernel 4: 256x256-tile GEMM — R13 schedule, RAW barriers + peeled tail ----------
// Change vs R18: (1) raw __builtin_amdgcn_s_barrier() (no asm memory clobbers) so
// the 8 bH ds_reads issued in P1/P5 (not consumed by that phase's MFMA) can keep
// a counted lgkmcnt and drain under the MFMA cluster — R13's structure set this
// overlap up, its clobbered barriers suppressed it. s_barrier still orders LDS
// ops at compiler+HW level (R7/R9/R14 proven). (2) last iteration peeled: loop
// body has constant koffs (SGPR-folded), no per-iter wrap selects.

#define BAR() __builtin_amdgcn_s_barrier()
#define VMW(N) asm volatile("s_waitcnt vmcnt(" #N ")" ::: "memory")

template<int MQ, int NQ>
__device__ __forceinline__ void mmq(f4v (&acc)[8][4], const s8v (&a)[4][2], const s8v (&b)[2][2]) {
  __builtin_amdgcn_s_setprio(1);
#pragma unroll
  for (int mi = 0; mi < 4; ++mi)
#pragma unroll
    for (int ni = 0; ni < 2; ++ni)
#pragma unroll
      for (int q = 0; q < 2; ++q)
        acc[MQ * 4 + mi][NQ * 2 + ni] = __builtin_amdgcn_mfma_f32_16x16x32_bf16(
            a[mi][q], b[ni][q], acc[MQ * 4 + mi][NQ * 2 + ni], 0, 0, 0);
  __builtin_amdgcn_s_setprio(0);
}

__global__ __launch_bounds__(512, 2) void gemm8(const unsigned short* __restrict__ A,
                                                const unsigned short* __restrict__ B,
                                                float* __restrict__ C) {
  constexpr int N = 4096, K = 4096;
  constexpr int NT = K / 64;
  constexpr int NITER = NT / 2;     // 32 iters, 2 K-tiles each
  constexpr int NXT = N / 256;

  __shared__ unsigned short lds[65536];   // 128 KiB

  const int tid  = threadIdx.x;
  const int lane = tid & 63;
  const int wid  = tid >> 6;
  const int wm   = wid >> 2;
  const int wn   = wid & 3;

  const int cpx = (int)gridDim.x >> 3;
  const int wg  = ((int)blockIdx.x & 7) * cpx + ((int)blockIdx.x >> 3);
  const long bm = (long)(wg / NXT) * 256;
  const long bn = (long)(wg % NXT) * 256;

  const int srow = tid >> 3;
  const int scol = ((tid & 7) ^ (srow & 7)) * 8;
  const unsigned short* gA = A + (bm + srow) * (size_t)K + scol;
  const unsigned short* gB = B + (bn + srow) * (size_t)K + scol;
  const size_t half64 = 64 * (size_t)K;
  const size_t k128   = 128 * (size_t)K;

#define STG(gp, koff, ldsU) do {                                  \
    const unsigned short* g_ = (gp) + (koff);                     \
    gll16(g_,          &lds[(ldsU) + tid * 8]);                   \
    gll16(g_ + half64, &lds[(ldsU) + 4096 + tid * 8]);            \
  } while (0)

  const int fr = lane & 15;
  const int ks = lane >> 4;
  const int f7 = fr & 7;
  const int sx0 = (ks ^ f7) * 8;
  const int sx1 = ((ks | 4) ^ f7) * 8;
  const int arow = (wm * 64 + fr) * 64;
  const int brow = (wn * 32 + fr) * 64;

#define RDA(MQ, bufU) do {                                                   \
    const unsigned short* p_ = &lds[(bufU) + (MQ) * 8192 + arow];            \
    a[0][0] = *(const s8v*)(p_ + sx0);        a[0][1] = *(const s8v*)(p_ + sx1); \
    a[1][0] = *(const s8v*)(p_ + 1024 + sx0); a[1][1] = *(const s8v*)(p_ + 1024 + sx1); \
    a[2][0] = *(const s8v*)(p_ + 2048 + sx0); a[2][1] = *(const s8v*)(p_ + 2048 + sx1); \
    a[3][0] = *(const s8v*)(p_ + 3072 + sx0); a[3][1] = *(const s8v*)(p_ + 3072 + sx1); \
  } while (0)
#define RDB(dst, NQ, bufU) do {                                              \
    const unsigned short* p_ = &lds[(bufU) + 16384 + (NQ) * 8192 + brow];    \
    dst[0][0] = *(const s8v*)(p_ + sx0);        dst[0][1] = *(const s8v*)(p_ + sx1); \
    dst[1][0] = *(const s8v*)(p_ + 1024 + sx0); dst[1][1] = *(const s8v*)(p_ + 1024 + sx1); \
  } while (0)

  f4v acc[8][4];
#pragma unroll
  for (int m = 0; m < 8; ++m)
#pragma unroll
    for (int n = 0; n < 4; ++n) acc[m][n] = (f4v)0.0f;

  // prologue: tile0 all 4 halves -> buf0; Alo(t1) -> buf1
  STG(gA,        0, 0);
  STG(gA + k128, 0, 8192);
  STG(gB,        0, 16384);
  STG(gB + k128, 0, 24576);
  STG(gA,        64, 32768);
  VMW(2);          // tile0's 8 loads drained; Alo(t1) flies
  BAR();

  s8v a[4][2], bL[2][2], bH[2][2];

  for (int i = 0; i < NITER - 1; ++i) {
    // ---- P1: pre {aLo,bL,bH}(c0); STG Blo(c1); MM(0,0) ----
    RDA(0, 0); RDB(bL, 0, 0); RDB(bH, 1, 0);
    STG(gB, 64, 32768 + 16384);
    BAR(); mmq<0, 0>(acc, a, bL);
    // ---- P2: STG Ahi(c1)+Bhi(c1); MM(0,1); post-read aHi(c0) ----
    STG(gA + k128, 64, 32768 + 8192);
    STG(gB + k128, 64, 32768 + 24576);
    BAR(); mmq<0, 1>(acc, a, bH);
    RDA(1, 0);
    // ---- P3: MM(1,0) ----
    BAR(); mmq<1, 0>(acc, a, bL);
    // ---- P4: STG Alo(c0+2); MM(1,1); VMW(2) lands ALL c1; pub ----
    STG(gA, 128, 0);
    BAR(); mmq<1, 1>(acc, a, bH);
    VMW(2); BAR();
    // ---- P5: pre {aLo,bL,bH}(c1); STG Blo(c0+2); MM(0,0) ----
    RDA(0, 32768); RDB(bL, 0, 32768); RDB(bH, 1, 32768);
    STG(gB, 128, 16384);
    BAR(); mmq<0, 0>(acc, a, bL);
    // ---- P6: STG Ahi(c0+2)+Bhi(c0+2); MM(0,1); post-read aHi(c1) ----
    STG(gA + k128, 128, 8192);
    STG(gB + k128, 128, 24576);
    BAR(); mmq<0, 1>(acc, a, bH);
    RDA(1, 32768);
    // ---- P7: MM(1,0) ----
    BAR(); mmq<1, 0>(acc, a, bL);
    // ---- P8: STG Alo(c1+2); MM(1,1); VMW(2) lands ALL c0+2; pub ----
    STG(gA, 192, 32768);
    BAR(); mmq<1, 1>(acc, a, bH);
    VMW(2); BAR();

    gA += 128; gB += 128;
  }
  // ---- peeled last iteration: dummy stages wrap to in-bounds offsets ----
  {
    RDA(0, 0); RDB(bL, 0, 0); RDB(bH, 1, 0);
    STG(gB, 64, 32768 + 16384);
    BAR(); mmq<0, 0>(acc, a, bL);
    STG(gA + k128, 64, 32768 + 8192);
    STG(gB + k128, 64, 32768 + 24576);
    BAR(); mmq<0, 1>(acc, a, bH);
    RDA(1, 0);
    BAR(); mmq<1, 0>(acc, a, bL);
    STG(gA, 0, 0);                      // dummy (wrapped)
    BAR(); mmq<1, 1>(acc, a, bH);
    VMW(2); BAR();
    RDA(0, 32768); RDB(bL, 0, 32768); RDB(bH, 1, 32768);
    STG(gB, 0, 16384);                  // dummy
    BAR(); mmq<0, 0>(acc, a, bL);
    STG(gA + k128, 0, 8192);            // dummy
    STG(gB + k128, 0, 24576);           // dummy
    BAR(); mmq<0, 1>(acc, a, bH);
    RDA(1, 32768);
    BAR(); mmq<1, 0>(acc, a, bL);
    STG(gA, 0, 32768);                  // dummy
    BAR(); mmq<1, 1>(acc, a, bH);
    VMW(2); BAR();
  }
  VMW(0);          // drain dummy prefetches

#pragma unroll
  for (int mq = 0; mq < 2; ++mq)
#pragma unroll
    for (int mi = 0; mi < 4; ++mi)
#pragma unroll
      for (int nq = 0; nq < 2; ++nq)
#pragma unroll
        for (int ni = 0; ni < 2; ++ni) {
          const size_t row0 = bm + mq * 128 + wm * 64 + mi * 16 + ks * 4;
          const size_t col  = bn + nq * 128 + wn * 32 + ni * 16 + fr;
          float* cp = C + row0 * (size_t)N + col;
          f4v v = acc[mq * 4 + mi][nq * 2 + ni];
          cp[0] = v[0]; cp[N] = v[1]; cp[2 * (size_t)N] = v[2]; cp[3 * (size_t)N] = v[3];
        }
#undef STG
#undef RDA
#undef RDB
}

// ---------- launch ----------
extern "C" void kernel_launch(void* const* d_in, const int* in_sizes, int n_in,
                              void* d_out, int out_size, void* d_ws, size_t ws_size,
                              hipStream_t stream) {
  const float* x  = (const float*)d_in[0];   // [8192,4096]
  const float* c0 = (const float*)d_in[1];   // [1,16,16,64]
  const float* c1 = (const float*)d_in[2];   // [64,16,16,64]
  const float* c2 = (const float*)d_in[3];   // [64,16,16,1]
  float* out = (float*)d_out;                // [8192,4096] fp32

  char* ws = (char*)d_ws;
  unsigned short* T    = (unsigned short*)ws;                       // 8 MB  bf16 [256][16384]
  unsigned short* c2t  = (unsigned short*)(ws + (8u << 20));        // 32 KB bf16 [256][64]
  unsigned short* c0bf = (unsigned short*)(ws + (8u << 20) + 65536);// 32 KB bf16 [256][64]
  unsigned short* c1t  = (unsigned short*)(ws + (9u << 20));        // 2 MB  bf16 [16384][64]
  unsigned short* Wb   = (unsigned short*)(ws + (16u << 20));       // 32 MB bf16 [4096][4096]
  unsigned short* xb   = (unsigned short*)(ws + (48u << 20));       // 64 MB bf16 [8192][4096]

  hipLaunchKernelGGL(cast_bf16, dim3(16384), dim3(256), 0, stream, x, xb);
  hipLaunchKernelGGL(cast_c0,   dim3(8),     dim3(256), 0, stream, c0, c0bf);
  hipLaunchKernelGGL(tc1,       dim3(64),    dim3(256), 0, stream, c1, c1t);
  hipLaunchKernelGGL(tgemm,     dim3(64, 2), dim3(512), 0, stream, c0bf, c1t, T);
  hipLaunchKernelGGL(transc2,   dim3(16),    dim3(256), 0, stream, c2, c2t);
  hipLaunchKernelGGL(buildW3,   dim3(256),   dim3(256), 0, stream, T, c2t, Wb);
  hipLaunchKernelGGL(gemm8,     dim3(512),   dim3(512), 0, stream, xb, Wb, out);
}

// Round 21
// 271.927 us; speedup vs baseline: 1.8616x; 1.0143x over previous
//
#include <hip/hip_runtime.h>

// ---------- types ----------
typedef __attribute__((ext_vector_type(8))) short  s8v;    // 8 bf16 (as shorts) = 4 VGPR
typedef __attribute__((ext_vector_type(8))) unsigned short us8;
typedef __attribute__((ext_vector_type(4))) unsigned short us4;
typedef __attribute__((ext_vector_type(4))) float  f4v;    // MFMA accumulator

// float -> bf16 round-to-nearest-even (inputs are finite)
__device__ __forceinline__ unsigned short f2bf(float f) {
  unsigned int u = __builtin_bit_cast(unsigned int, f);
  u += 0x7fffu + ((u >> 16) & 1u);
  return (unsigned short)(u >> 16);
}

// async global->LDS, 16B per lane; offset arg must stay 0 (only verified mode).
__device__ __forceinline__ void gll16(const void* g, void* l) {
  __builtin_amdgcn_global_load_lds(
      (const __attribute__((address_space(1))) unsigned int*)g,
      (__attribute__((address_space(3))) unsigned int*)l, 16, 0, 0);
}

// ---------- kernel 1: x fp32 -> bf16 (33.5M elems) ----------
__global__ __launch_bounds__(256) void cast_bf16(const float* __restrict__ in,
                                                 unsigned short* __restrict__ out) {
  const size_t i = (size_t)blockIdx.x * 256 + threadIdx.x;
  const f4v* p = (const f4v*)in;
  f4v a = p[2 * i];
  f4v b = p[2 * i + 1];
  us8 r;
  r[0] = f2bf(a[0]); r[1] = f2bf(a[1]); r[2] = f2bf(a[2]); r[3] = f2bf(a[3]);
  r[4] = f2bf(b[0]); r[5] = f2bf(b[1]); r[6] = f2bf(b[2]); r[7] = f2bf(b[3]);
  *(us8*)&out[i * 8] = r;
}

// ---------- kernel 2: prep — fused {tc1 | cast_c0 | transc2} by block index ----------
// blocks 0..63  : tc1   — transpose-cast c1[k=64][n=16384] fp32 -> c1t[n][k] bf16
// blocks 64..71 : cast_c0 — c0 fp32 -> bf16 (16384 elems)
// blocks 72..87 : transc2 — c2t[n=o3*16+i3][k=r2] bf16 = c2[r2][n]
__global__ __launch_bounds__(256) void prep(const float* __restrict__ c0,
                                            const float* __restrict__ c1,
                                            const float* __restrict__ c2,
                                            unsigned short* __restrict__ c0bf,
                                            unsigned short* __restrict__ c1t,
                                            unsigned short* __restrict__ c2t) {
  __shared__ float Tl[16384];   // [k=64][n=256] (tc1 role only)
  const int tid = threadIdx.x;
  const int blk = blockIdx.x;

  if (blk < 64) {
    const int nb = blk;
#pragma unroll
    for (int j = 0; j < 16; ++j) {
      const int c = j * 256 + tid;
      const int k = c >> 6, nq = c & 63;
      *(f4v*)&Tl[k * 256 + nq * 4] =
          *(const f4v*)(c1 + (size_t)k * 16384 + nb * 256 + nq * 4);
    }
    __syncthreads();
    const int nn = tid;
    unsigned short* dst = c1t + (size_t)(nb * 256 + nn) * 64;
#pragma unroll
    for (int kq = 0; kq < 16; ++kq) {
      us4 o;
#pragma unroll
      for (int r = 0; r < 4; ++r) o[r] = f2bf(Tl[(kq * 4 + r) * 256 + nn]);
      *(us4*)&dst[kq * 4] = o;
    }
  } else if (blk < 72) {
    const size_t i = (size_t)(blk - 64) * 256 + tid;
    const f4v* p = (const f4v*)c0;
    f4v a = p[2 * i];
    f4v b = p[2 * i + 1];
    us8 r;
    r[0] = f2bf(a[0]); r[1] = f2bf(a[1]); r[2] = f2bf(a[2]); r[3] = f2bf(a[3]);
    r[4] = f2bf(b[0]); r[5] = f2bf(b[1]); r[6] = f2bf(b[2]); r[7] = f2bf(b[3]);
    *(us8*)&c0bf[i * 8] = r;
  } else {
    const int n = (blk - 72) * 16 + (tid >> 4);
    const int j = tid & 15;
    us4 o;
#pragma unroll
    for (int q = 0; q < 4; ++q) o[q] = f2bf(c2[(j * 4 + q) * 256 + n]);
    *(us4*)&c2t[(size_t)n * 64 + j * 4] = o;
  }
}

// ---------- kernel 3: tgemm — T[m=256][n=16384] = c0bf[m][k=64] * c1t[n][k]^T ----------
__global__ __launch_bounds__(512) void tgemm(const unsigned short* __restrict__ c0bf,
                                             const unsigned short* __restrict__ c1t,
                                             unsigned short* __restrict__ T) {
  __shared__ unsigned short sA[8192];    // [128 m][64 k] swizzled
  __shared__ unsigned short sB[16384];   // [256 n][64 k] swizzled

  const int tid = threadIdx.x;
  const int nb = blockIdx.x, mb = blockIdx.y;

#pragma unroll
  for (int j = 0; j < 2; ++j) {
    const int c = j * 512 + tid;
    const int row = c >> 3, sl = c & 7;
    *(us8*)&sA[row * 64 + ((sl ^ (row & 7)) << 3)] =
        *(const us8*)(c0bf + (size_t)(mb * 128 + row) * 64 + sl * 8);
  }
#pragma unroll
  for (int j = 0; j < 4; ++j) {
    const int c = j * 512 + tid;
    const int row = c >> 3, sl = c & 7;
    *(us8*)&sB[row * 64 + ((sl ^ (row & 7)) << 3)] =
        *(const us8*)(c1t + (size_t)(nb * 256 + row) * 64 + sl * 8);
  }
  __syncthreads();

  const int lane = tid & 63, wid = tid >> 6;
  const int wm = wid >> 2, wn = wid & 3;
  const int fr = lane & 15, ks = lane >> 4;
  const int f7 = fr & 7;
  const int sx0 = (ks ^ f7) * 8;
  const int sx1 = ((ks | 4) ^ f7) * 8;

  s8v a[4][2], b[4][2];
#pragma unroll
  for (int mi = 0; mi < 4; ++mi) {
    const unsigned short* p = &sA[(wm * 64 + mi * 16 + fr) * 64];
    a[mi][0] = *(const s8v*)(p + sx0);
    a[mi][1] = *(const s8v*)(p + sx1);
  }
#pragma unroll
  for (int ni = 0; ni < 4; ++ni) {
    const unsigned short* p = &sB[(wn * 64 + ni * 16 + fr) * 64];
    b[ni][0] = *(const s8v*)(p + sx0);
    b[ni][1] = *(const s8v*)(p + sx1);
  }

  f4v acc[4][4];
#pragma unroll
  for (int mi = 0; mi < 4; ++mi)
#pragma unroll
    for (int ni = 0; ni < 4; ++ni) {
      acc[mi][ni] = (f4v)0.f;
      acc[mi][ni] = __builtin_amdgcn_mfma_f32_16x16x32_bf16(a[mi][0], b[ni][0], acc[mi][ni], 0, 0, 0);
      acc[mi][ni] = __builtin_amdgcn_mfma_f32_16x16x32_bf16(a[mi][1], b[ni][1], acc[mi][ni], 0, 0, 0);
    }

#pragma unroll
  for (int mi = 0; mi < 4; ++mi)
#pragma unroll
    for (int ni = 0; ni < 4; ++ni) {
      const int row0 = mb * 128 + wm * 64 + mi * 16 + ks * 4;
      const size_t col = (size_t)nb * 256 + wn * 64 + ni * 16 + fr;
#pragma unroll
      for (int r = 0; r < 4; ++r)
        T[(size_t)(row0 + r) * 16384 + col] = f2bf(acc[mi][ni][r]);
    }
}

// ---------- kernel 4: buildW3 — 256x256x64 MFMA mini-GEMM per (o1,o2) ----------
__global__ __launch_bounds__(256) void buildW3(const unsigned short* __restrict__ T,
                                               const unsigned short* __restrict__ c2t,
                                               unsigned short* __restrict__ W) {
  __shared__ unsigned short sT[16384];
  __shared__ unsigned short sC[16384];

  const int tid = threadIdx.x;
  const int o1 = blockIdx.x >> 4, o2 = blockIdx.x & 15;

#pragma unroll
  for (int j = 0; j < 8; ++j) {
    const int c = j * 256 + tid;
    const int m = c >> 3, sl = c & 7;
    const int dst = m * 64 + ((sl ^ (m & 7)) << 3);
    *(us8*)&sT[dst] = *(const us8*)(T + (size_t)(o1 * 16 + (m >> 4)) * 16384 +
                                    (o2 * 16 + (m & 15)) * 64 + sl * 8);
    *(us8*)&sC[dst] = *(const us8*)(c2t + (size_t)m * 64 + sl * 8);
  }
  __syncthreads();

  const int lane = tid & 63, wid = tid >> 6;
  const int fr = lane & 15, ks = lane >> 4;
  const int f7 = fr & 7;
  const int sx0 = ((ks ^ f7) << 3);
  const int sx1 = (((4 + ks) ^ f7) << 3);

  s8v a[4][2];
#pragma unroll
  for (int mi = 0; mi < 4; ++mi) {
    const unsigned short* p = &sT[(wid * 64 + mi * 16 + fr) * 64];
    a[mi][0] = *(const s8v*)(p + sx0);
    a[mi][1] = *(const s8v*)(p + sx1);
  }
#pragma unroll
  for (int nt = 0; nt < 16; ++nt) {
    const unsigned short* p = &sC[(nt * 16 + fr) * 64];
    const s8v b0 = *(const s8v*)(p + sx0);
    const s8v b1 = *(const s8v*)(p + sx1);
#pragma unroll
    for (int mi = 0; mi < 4; ++mi) {
      f4v acc = (f4v)0.f;
      acc = __builtin_amdgcn_mfma_f32_16x16x32_bf16(a[mi][0], b0, acc, 0, 0, 0);
      acc = __builtin_amdgcn_mfma_f32_16x16x32_bf16(a[mi][1], b1, acc, 0, 0, 0);
      unsigned short* wp = W + (size_t)(o1 * 256 + o2 * 16 + nt) * 4096 +
                           (wid * 4 + mi) * 256 + fr;
#pragma unroll
      for (int r = 0; r < 4; ++r) wp[(ks * 4 + r) * 16] = f2bf(acc[r]);
    }
  }
}

// ---------- kernel 5: 256x256-tile GEMM — locked best (R13 schedule, raw barriers, peeled tail) ----------
#define BAR() __builtin_amdgcn_s_barrier()
#define VMW(N) asm volatile("s_waitcnt vmcnt(" #N ")" ::: "memory")

template<int MQ, int NQ>
__device__ __forceinline__ void mmq(f4v (&acc)[8][4], const s8v (&a)[4][2], const s8v (&b)[2][2]) {
  __builtin_amdgcn_s_setprio(1);
#pragma unroll
  for (int mi = 0; mi < 4; ++mi)
#pragma unroll
    for (int ni = 0; ni < 2; ++ni)
#pragma unroll
      for (int q = 0; q < 2; ++q)
        acc[MQ * 4 + mi][NQ * 2 + ni] = __builtin_amdgcn_mfma_f32_16x16x32_bf16(
            a[mi][q], b[ni][q], acc[MQ * 4 + mi][NQ * 2 + ni], 0, 0, 0);
  __builtin_amdgcn_s_setprio(0);
}

__global__ __launch_bounds__(512, 2) void gemm8(const unsigned short* __restrict__ A,
                                                const unsigned short* __restrict__ B,
                                                float* __restrict__ C) {
  constexpr int N = 4096, K = 4096;
  constexpr int NT = K / 64;
  constexpr int NITER = NT / 2;     // 32 iters, 2 K-tiles each
  constexpr int NXT = N / 256;

  __shared__ unsigned short lds[65536];   // 128 KiB

  const int tid  = threadIdx.x;
  const int lane = tid & 63;
  const int wid  = tid >> 6;
  const int wm   = wid >> 2;
  const int wn   = wid & 3;

  const int cpx = (int)gridDim.x >> 3;
  const int wg  = ((int)blockIdx.x & 7) * cpx + ((int)blockIdx.x >> 3);
  const long bm = (long)(wg / NXT) * 256;
  const long bn = (long)(wg % NXT) * 256;

  const int srow = tid >> 3;
  const int scol = ((tid & 7) ^ (srow & 7)) * 8;
  const unsigned short* gA = A + (bm + srow) * (size_t)K + scol;
  const unsigned short* gB = B + (bn + srow) * (size_t)K + scol;
  const size_t half64 = 64 * (size_t)K;
  const size_t k128   = 128 * (size_t)K;

#define STG(gp, koff, ldsU) do {                                  \
    const unsigned short* g_ = (gp) + (koff);                     \
    gll16(g_,          &lds[(ldsU) + tid * 8]);                   \
    gll16(g_ + half64, &lds[(ldsU) + 4096 + tid * 8]);            \
  } while (0)

  const int fr = lane & 15;
  const int ks = lane >> 4;
  const int f7 = fr & 7;
  const int sx0 = (ks ^ f7) * 8;
  const int sx1 = ((ks | 4) ^ f7) * 8;
  const int arow = (wm * 64 + fr) * 64;
  const int brow = (wn * 32 + fr) * 64;

#define RDA(MQ, bufU) do {                                                   \
    const unsigned short* p_ = &lds[(bufU) + (MQ) * 8192 + arow];            \
    a[0][0] = *(const s8v*)(p_ + sx0);        a[0][1] = *(const s8v*)(p_ + sx1); \
    a[1][0] = *(const s8v*)(p_ + 1024 + sx0); a[1][1] = *(const s8v*)(p_ + 1024 + sx1); \
    a[2][0] = *(const s8v*)(p_ + 2048 + sx0); a[2][1] = *(const s8v*)(p_ + 2048 + sx1); \
    a[3][0] = *(const s8v*)(p_ + 3072 + sx0); a[3][1] = *(const s8v*)(p_ + 3072 + sx1); \
  } while (0)
#define RDB(dst, NQ, bufU) do {                                              \
    const unsigned short* p_ = &lds[(bufU) + 16384 + (NQ) * 8192 + brow];    \
    dst[0][0] = *(const s8v*)(p_ + sx0);        dst[0][1] = *(const s8v*)(p_ + sx1); \
    dst[1][0] = *(const s8v*)(p_ + 1024 + sx0); dst[1][1] = *(const s8v*)(p_ + 1024 + sx1); \
  } while (0)

  f4v acc[8][4];
#pragma unroll
  for (int m = 0; m < 8; ++m)
#pragma unroll
    for (int n = 0; n < 4; ++n) acc[m][n] = (f4v)0.0f;

  // prologue: tile0 all 4 halves -> buf0; Alo(t1) -> buf1
  STG(gA,        0, 0);
  STG(gA + k128, 0, 8192);
  STG(gB,        0, 16384);
  STG(gB + k128, 0, 24576);
  STG(gA,        64, 32768);
  VMW(2);          // tile0's 8 loads drained; Alo(t1) flies
  BAR();

  s8v a[4][2], bL[2][2], bH[2][2];

  for (int i = 0; i < NITER - 1; ++i) {
    // ---- P1: pre {aLo,bL,bH}(c0); STG Blo(c1); MM(0,0) ----
    RDA(0, 0); RDB(bL, 0, 0); RDB(bH, 1, 0);
    STG(gB, 64, 32768 + 16384);
    BAR(); mmq<0, 0>(acc, a, bL);
    // ---- P2: STG Ahi(c1)+Bhi(c1); MM(0,1); post-read aHi(c0) ----
    STG(gA + k128, 64, 32768 + 8192);
    STG(gB + k128, 64, 32768 + 24576);
    BAR(); mmq<0, 1>(acc, a, bH);
    RDA(1, 0);
    // ---- P3: MM(1,0) ----
    BAR(); mmq<1, 0>(acc, a, bL);
    // ---- P4: STG Alo(c0+2); MM(1,1); VMW(2) lands ALL c1; pub ----
    STG(gA, 128, 0);
    BAR(); mmq<1, 1>(acc, a, bH);
    VMW(2); BAR();
    // ---- P5: pre {aLo,bL,bH}(c1); STG Blo(c0+2); MM(0,0) ----
    RDA(0, 32768); RDB(bL, 0, 32768); RDB(bH, 1, 32768);
    STG(gB, 128, 16384);
    BAR(); mmq<0, 0>(acc, a, bL);
    // ---- P6: STG Ahi(c0+2)+Bhi(c0+2); MM(0,1); post-read aHi(c1) ----
    STG(gA + k128, 128, 8192);
    STG(gB + k128, 128, 24576);
    BAR(); mmq<0, 1>(acc, a, bH);
    RDA(1, 32768);
    // ---- P7: MM(1,0) ----
    BAR(); mmq<1, 0>(acc, a, bL);
    // ---- P8: STG Alo(c1+2); MM(1,1); VMW(2) lands ALL c0+2; pub ----
    STG(gA, 192, 32768);
    BAR(); mmq<1, 1>(acc, a, bH);
    VMW(2); BAR();

    gA += 128; gB += 128;
  }
  // ---- peeled last iteration: dummy stages wrap to in-bounds offsets ----
  {
    RDA(0, 0); RDB(bL, 0, 0); RDB(bH, 1, 0);
    STG(gB, 64, 32768 + 16384);
    BAR(); mmq<0, 0>(acc, a, bL);
    STG(gA + k128, 64, 32768 + 8192);
    STG(gB + k128, 64, 32768 + 24576);
    BAR(); mmq<0, 1>(acc, a, bH);
    RDA(1, 0);
    BAR(); mmq<1, 0>(acc, a, bL);
    STG(gA, 0, 0);                      // dummy (wrapped)
    BAR(); mmq<1, 1>(acc, a, bH);
    VMW(2); BAR();
    RDA(0, 32768); RDB(bL, 0, 32768); RDB(bH, 1, 32768);
    STG(gB, 0, 16384);                  // dummy
    BAR(); mmq<0, 0>(acc, a, bL);
    STG(gA + k128, 0, 8192);            // dummy
    STG(gB + k128, 0, 24576);           // dummy
    BAR(); mmq<0, 1>(acc, a, bH);
    RDA(1, 32768);
    BAR(); mmq<1, 0>(acc, a, bL);
    STG(gA, 0, 32768);                  // dummy
    BAR(); mmq<1, 1>(acc, a, bH);
    VMW(2); BAR();
  }
  VMW(0);          // drain dummy prefetches

#pragma unroll
  for (int mq = 0; mq < 2; ++mq)
#pragma unroll
    for (int mi = 0; mi < 4; ++mi)
#pragma unroll
      for (int nq = 0; nq < 2; ++nq)
#pragma unroll
        for (int ni = 0; ni < 2; ++ni) {
          const size_t row0 = bm + mq * 128 + wm * 64 + mi * 16 + ks * 4;
          const size_t col  = bn + nq * 128 + wn * 32 + ni * 16 + fr;
          float* cp = C + row0 * (size_t)N + col;
          f4v v = acc[mq * 4 + mi][nq * 2 + ni];
          cp[0] = v[0]; cp[N] = v[1]; cp[2 * (size_t)N] = v[2]; cp[3 * (size_t)N] = v[3];
        }
#undef STG
#undef RDA
#undef RDB
}

// ---------- launch ----------
extern "C" void kernel_launch(void* const* d_in, const int* in_sizes, int n_in,
                              void* d_out, int out_size, void* d_ws, size_t ws_size,
                              hipStream_t stream) {
  const float* x  = (const float*)d_in[0];   // [8192,4096]
  const float* c0 = (const float*)d_in[1];   // [1,16,16,64]
  const float* c1 = (const float*)d_in[2];   // [64,16,16,64]
  const float* c2 = (const float*)d_in[3];   // [64,16,16,1]
  float* out = (float*)d_out;                // [8192,4096] fp32

  char* ws = (char*)d_ws;
  unsigned short* T    = (unsigned short*)ws;                       // 8 MB  bf16 [256][16384]
  unsigned short* c2t  = (unsigned short*)(ws + (8u << 20));        // 32 KB bf16 [256][64]
  unsigned short* c0bf = (unsigned short*)(ws + (8u << 20) + 65536);// 32 KB bf16 [256][64]
  unsigned short* c1t  = (unsigned short*)(ws + (9u << 20));        // 2 MB  bf16 [16384][64]
  unsigned short* Wb   = (unsigned short*)(ws + (16u << 20));       // 32 MB bf16 [4096][4096]
  unsigned short* xb   = (unsigned short*)(ws + (48u << 20));       // 64 MB bf16 [8192][4096]

  hipLaunchKernelGGL(cast_bf16, dim3(16384), dim3(256), 0, stream, x, xb);
  hipLaunchKernelGGL(prep,      dim3(88),    dim3(256), 0, stream, c0, c1, c2, c0bf, c1t, c2t);
  hipLaunchKernelGGL(tgemm,     dim3(64, 2), dim3(512), 0, stream, c0bf, c1t, T);
  hipLaunchKernelGGL(buildW3,   dim3(256),   dim3(256), 0, stream, T, c2t, Wb);
  hipLaunchKernelGGL(gemm8,     dim3(512),   dim3(512), 0, stream, xb, Wb, out);
}